// Round 3
// baseline (754.076 us; speedup 1.0000x reference)
//
#include <hip/hip_runtime.h>
#include <math.h>

// Problem constants
#define B_    64
#define S_    4096
#define HID   64
#define LIFT  256
#define MODES 16
#define NL    4

// Workspace layout (float offsets).
#define OFF_H     0
#define OFF_TAB   (B_*HID*S_)                 // float2[4096] = 8192 floats
#define OFF_XFR   (OFF_TAB  + 8192)
#define OFF_XFI   (OFF_XFR  + B_*HID*MODES)   // 65536 each
#define OFF_YKR   (OFF_XFI  + B_*HID*MODES)
#define OFF_YKI   (OFF_YKR  + B_*HID*MODES)
#define OFF_W2T   (OFF_YKI  + B_*HID*MODES)
#define OFF_SKWT  (OFF_W2T  + LIFT*HID)       // 16384
#define OFF_PW1T  (OFF_SKWT + NL*HID*HID)     // 16384
#define OFF_PART  (OFF_PW1T + HID*LIFT)       // 24576 floats: 64*32*4*3

__device__ __forceinline__ float gelu_f(float x) {
  return 0.5f * x * (1.0f + erff(x * 0.70710678118654752440f));
}

// ---------------------------------------------------------------- init ----
__global__ void k_init(const float* __restrict__ lift_w2,
                       const float* __restrict__ skip_w,
                       const float* __restrict__ proj_w1,
                       float* __restrict__ ws) {
  float2* tab  = (float2*)(ws + OFF_TAB);
  float*  w2T  = ws + OFF_W2T;
  float*  skwT = ws + OFF_SKWT;
  float*  pw1T = ws + OFF_PW1T;
  int idx = blockIdx.x * 256 + threadIdx.x;
  int stride = gridDim.x * 256;
  for (int k = idx; k < 4096; k += stride) {
    double th = (2.0 * 3.14159265358979323846 / 4096.0) * (double)k;
    double sn, cn; sincos(th, &sn, &cn);
    tab[k] = make_float2((float)cn, (float)sn);
  }
  for (int k = idx; k < LIFT * HID; k += stride) {     // w2T[c2][o]
    int c2 = k / HID, o = k % HID;
    w2T[k] = lift_w2[o * LIFT + c2];
  }
  for (int k = idx; k < NL * HID * HID; k += stride) { // skwT[l][c][o]
    int l = k / (HID * HID); int r = k % (HID * HID);
    int c = r / HID, o = r % HID;
    skwT[k] = skip_w[l * HID * HID + o * HID + c];
  }
  for (int k = idx; k < HID * LIFT; k += stride) {     // pw1T[c][c2]
    int c = k / LIFT, c2 = k % LIFT;
    pw1T[k] = proj_w1[c2 * HID + c];
  }
}

// ---------------------------------------------------------------- lift ----
// grid (S/256, B), block 256. Lane owns one s-column; no LDS, no barriers.
// h[b][o][s] = b2[o] + sum_c2 w2T[c2][o] * gelu(w1[c2].x*x0 + w1[c2].y*x1 + b1[c2])
__global__ __launch_bounds__(256) void k_lift(
    const float* __restrict__ x, const float* __restrict__ w1,
    const float* __restrict__ b1, const float* __restrict__ b2,
    const float* __restrict__ w2T, float* __restrict__ h) {
  int tid = threadIdx.x;
  int b = blockIdx.y;
  int s = blockIdx.x * 256 + tid;
  float2 xv = ((const float2*)x)[b * S_ + s];
  float acc[64];
  #pragma unroll
  for (int o = 0; o < 64; ++o) acc[o] = b2[o];
  #pragma unroll 1
  for (int c2 = 0; c2 < 256; ++c2) {
    float t = gelu_f(w1[2 * c2] * xv.x + w1[2 * c2 + 1] * xv.y + b1[c2]);
    const float* __restrict__ wr = w2T + c2 * 64;
    #pragma unroll
    for (int o = 0; o < 64; ++o) acc[o] += wr[o] * t;
  }
  #pragma unroll
  for (int o = 0; o < 64; ++o)
    h[(b * HID + o) * S_ + s] = acc[o];
}

// --------------------------------------------------------- forward FFT ----
// grid (HID, B), block 256 = 4 waves. Radix-4 fold over s; wave w owns
// modes m ≡ w (mod 4): {w, w+4, w+8, w+12}. xf[b,i,m] = sum_s h e^{-2πims/S}.
__global__ __launch_bounds__(256) void k_fft_fwd(
    const float* __restrict__ h, const float2* __restrict__ tab,
    float* __restrict__ xfr, float* __restrict__ xfi) {
  __shared__ float hs[S_];          // 16 KB
  int tid = threadIdx.x;
  int i = blockIdx.x, b = blockIdx.y;
  int lane = tid & 63, w = tid >> 6;
  const float4* __restrict__ hp4 = (const float4*)(h + (size_t)(b * HID + i) * S_);
  #pragma unroll
  for (int j = 0; j < 4; ++j)
    ((float4*)hs)[tid + j * 256] = hp4[tid + j * 256];
  __syncthreads();
  float ar[4], ai[4], pr[4], pi[4], rc[4], rs[4];
  #pragma unroll
  for (int jj = 0; jj < 4; ++jj) {
    int m = w + 4 * jj;
    ar[jj] = 0.f; ai[jj] = 0.f;
    float2 p = tab[(m * lane) & 4095];
    pr[jj] = p.x; pi[jj] = -p.y;          // e^{-iθ m lane}
    float2 r = tab[(m * 64) & 4095];
    rc[jj] = r.x; rs[jj] = -r.y;          // step e^{-iθ m 64}
  }
  if (w == 0 || w == 2) {
    for (int k = 0; k < 16; ++k) {
      int base = k * 64 + lane;
      float h0 = hs[base], h1 = hs[base + 1024],
            h2 = hs[base + 2048], h3 = hs[base + 3072];
      float F = (w == 0) ? (h0 + h2) + (h1 + h3) : (h0 + h2) - (h1 + h3);
      #pragma unroll
      for (int jj = 0; jj < 4; ++jj) {
        ar[jj] += F * pr[jj];
        ai[jj] += F * pi[jj];
        float np = pr[jj] * rc[jj] - pi[jj] * rs[jj];
        pi[jj]   = pr[jj] * rs[jj] + pi[jj] * rc[jj];
        pr[jj] = np;
      }
    }
  } else {
    for (int k = 0; k < 16; ++k) {
      int base = k * 64 + lane;
      float h0 = hs[base], h1 = hs[base + 1024],
            h2 = hs[base + 2048], h3 = hs[base + 3072];
      float Fr = h0 - h2;
      float Fi = (w == 1) ? -(h1 - h3) : (h1 - h3);
      #pragma unroll
      for (int jj = 0; jj < 4; ++jj) {
        ar[jj] += Fr * pr[jj] - Fi * pi[jj];
        ai[jj] += Fr * pi[jj] + Fi * pr[jj];
        float np = pr[jj] * rc[jj] - pi[jj] * rs[jj];
        pi[jj]   = pr[jj] * rs[jj] + pi[jj] * rc[jj];
        pr[jj] = np;
      }
    }
  }
  #pragma unroll
  for (int off = 32; off > 0; off >>= 1) {
    #pragma unroll
    for (int jj = 0; jj < 4; ++jj) {
      ar[jj] += __shfl_xor(ar[jj], off, 64);
      ai[jj] += __shfl_xor(ai[jj], off, 64);
    }
  }
  if (lane == 0) {
    int base = (b * HID + i) * MODES;
    #pragma unroll
    for (int jj = 0; jj < 4; ++jj) {
      int m = w + 4 * jj;
      xfr[base + m] = ar[jj];
      xfi[base + m] = ai[jj];   // m=0 path accumulates exact 0 (pi stays 0)
    }
  }
}

// ----------------------------------------------------------- mode mix ----
// grid (4, B), block 256. yk[b][m][o] = fac * sum_i xf[b,i,m]*w[i,o,m]
__global__ __launch_bounds__(256) void k_mix(
    const float* __restrict__ wr_, const float* __restrict__ wi_,
    const float* __restrict__ xfr, const float* __restrict__ xfi,
    float* __restrict__ ykr, float* __restrict__ yki) {
  int tid = threadIdx.x;
  int b = blockIdx.y, pp = blockIdx.x;
  __shared__ float xr[HID * MODES], xi[HID * MODES];
  for (int u = tid; u < HID * MODES; u += 256) {
    xr[u] = xfr[b * HID * MODES + u];
    xi[u] = xfi[b * HID * MODES + u];
  }
  __syncthreads();
  const float invS = 1.0f / (float)S_;
  int o = pp * 16 + (tid >> 4), m = tid & 15;
  float yr = 0.f, yi = 0.f;
  for (int i2 = 0; i2 < HID; ++i2) {
    float wr = wr_[(i2 * HID + o) * MODES + m];
    float wi = wi_[(i2 * HID + o) * MODES + m];
    float xrv = xr[i2 * MODES + m], xiv = xi[i2 * MODES + m];
    yr += xrv * wr - xiv * wi;
    yi += xrv * wi + xiv * wr;
  }
  float fac = (m == 0) ? invS : 2.f * invS;
  ykr[(b * 16 + m) * 64 + o] = yr * fac;
  yki[(b * 16 + m) * 64 + o] = yi * fac;
}

// --------------------------------------------- irfft + skip + (gelu) ----
// grid (S/128, B), block 256, in-place h update. No LDS; one barrier
// separates all in-place reads from stores (vmcnt drain at __syncthreads).
// acc[o][j] = skb[o] + yk0r[o] + sum_{m>=1}(Yr[m][o]cos(θms) - Yi[m][o]sin(θms))
//           + sum_c skwT[c][o] h[c][s]
template <bool ACT>
__global__ __launch_bounds__(256) void k_spec_skip(
    const float* __restrict__ skwT, const float* __restrict__ skb,
    const float* __restrict__ ykr, const float* __restrict__ yki,
    const float2* __restrict__ tab, float* __restrict__ h) {
  int tid = threadIdx.x;
  int s0 = blockIdx.x * 128, b = blockIdx.y;
  const int wo = __builtin_amdgcn_readfirstlane((tid >> 6) << 4);
  const int sl = (tid & 63) * 2;
  const int s = s0 + sl;
  // base rotation e^{+iθ s_j} for the two columns; running (cos,sin)(m θ s_j)
  float2 t0 = tab[s], t1 = tab[s + 1];
  float bc0 = t0.x, bs0 = t0.y, bc1 = t1.x, bs1 = t1.y;
  float cm0 = bc0, sm0 = bs0, cm1 = bc1, sm1 = bs1;
  float acc[16][2];
  {
    const float* __restrict__ y0 = ykr + (b * 16) * 64 + wo;
    const float* __restrict__ bb = skb + wo;
    #pragma unroll
    for (int o = 0; o < 16; ++o) {
      float v = bb[o] + y0[o];
      acc[o][0] = v; acc[o][1] = v;
    }
  }
  #pragma unroll 1
  for (int m = 1; m < 16; ++m) {
    const float* __restrict__ yr = ykr + (b * 16 + m) * 64 + wo;
    const float* __restrict__ yi = yki + (b * 16 + m) * 64 + wo;
    #pragma unroll
    for (int o = 0; o < 16; ++o) {
      acc[o][0] += yr[o] * cm0 - yi[o] * sm0;
      acc[o][1] += yr[o] * cm1 - yi[o] * sm1;
    }
    float n0 = cm0 * bc0 - sm0 * bs0; sm0 = sm0 * bc0 + cm0 * bs0; cm0 = n0;
    float n1 = cm1 * bc1 - sm1 * bs1; sm1 = sm1 * bc1 + cm1 * bs1; cm1 = n1;
  }
  // skip GEMM K=64, h read direct from global (coalesced float2 per lane)
  const float* __restrict__ hcol = h + (size_t)b * HID * S_ + s;
  #pragma unroll 4
  for (int c = 0; c < 64; ++c) {
    const float* __restrict__ wr = skwT + c * 64 + wo;
    float2 hv = *(const float2*)(hcol + (size_t)c * S_);
    #pragma unroll
    for (int o = 0; o < 16; ++o) {
      acc[o][0] += wr[o] * hv.x;
      acc[o][1] += wr[o] * hv.y;
    }
  }
  if (ACT) {
    #pragma unroll
    for (int o = 0; o < 16; ++o) {
      acc[o][0] = gelu_f(acc[o][0]);
      acc[o][1] = gelu_f(acc[o][1]);
    }
  }
  __syncthreads();   // all waves' loads drained before any in-place store
  float* __restrict__ hout = h + ((size_t)b * HID + wo) * S_ + s;
  #pragma unroll
  for (int o = 0; o < 16; ++o)
    *(float2*)(hout + (size_t)o * S_) = make_float2(acc[o][0], acc[o][1]);
}

// ------------------------------------------------- projection + mean ----
// grid (S/128, B, 4). Block handles 64 c2-rows (z picks which) x 128 s.
__global__ __launch_bounds__(256) void k_proj(
    const float* __restrict__ pw1T, const float* __restrict__ pb1,
    const float* __restrict__ pw2, const float* __restrict__ h,
    float* __restrict__ part) {
  __shared__ float hs[64 * 128];
  __shared__ float red[12];
  int tid = threadIdx.x;
  int s0 = blockIdx.x * 128, b = blockIdx.y;
  int c2base = blockIdx.z * 64;
  const int wo = __builtin_amdgcn_readfirstlane((tid >> 6) << 4);
  const int sl = (tid & 63) * 2;
  #pragma unroll
  for (int i = 0; i < 8; ++i) {
    int c = i * 8 + (tid >> 5);
    int sq = (tid & 31) * 4;
    *(float4*)&hs[c * 128 + sq] = *(const float4*)&h[(b * HID + c) * S_ + s0 + sq];
  }
  float acc[16][2];
  #pragma unroll
  for (int o = 0; o < 16; ++o) { acc[o][0] = 0.f; acc[o][1] = 0.f; }
  __syncthreads();
  #pragma unroll 4
  for (int c = 0; c < 64; ++c) {
    const float* __restrict__ wrow = pw1T + c * LIFT + c2base + wo;
    float w[16];
    #pragma unroll
    for (int o = 0; o < 16; ++o) w[o] = wrow[o];
    float2 hv = *(const float2*)&hs[c * 128 + sl];
    #pragma unroll
    for (int o = 0; o < 16; ++o) {
      acc[o][0] += w[o] * hv.x;
      acc[o][1] += w[o] * hv.y;
    }
  }
  // epilogue: gelu + contract with pw2, reduce over s and c2
  const float* __restrict__ b1row = pb1 + c2base + wo;
  const float* __restrict__ p0row = pw2 + c2base + wo;
  const float* __restrict__ p1row = pw2 + 256 + c2base + wo;
  const float* __restrict__ p2row = pw2 + 512 + c2base + wo;
  float o0 = 0.f, o1 = 0.f, o2 = 0.f;
  #pragma unroll
  for (int o = 0; o < 16; ++o) {
    float bb = b1row[o];
    float t = gelu_f(acc[o][0] + bb) + gelu_f(acc[o][1] + bb);
    o0 += p0row[o] * t; o1 += p1row[o] * t; o2 += p2row[o] * t;
  }
  #pragma unroll
  for (int off = 32; off > 0; off >>= 1) {
    o0 += __shfl_xor(o0, off, 64);
    o1 += __shfl_xor(o1, off, 64);
    o2 += __shfl_xor(o2, off, 64);
  }
  int lane = tid & 63, wid = tid >> 6;
  if (lane == 0) { red[wid*3+0] = o0; red[wid*3+1] = o1; red[wid*3+2] = o2; }
  __syncthreads();
  if (tid < 3) {
    float s = red[tid] + red[3 + tid] + red[6 + tid] + red[9 + tid];
    part[((b * 32 + blockIdx.x) * 4 + blockIdx.z) * 3 + tid] = s;
  }
}

__global__ void k_final(const float* __restrict__ part,
                        const float* __restrict__ pb2,
                        float* __restrict__ out) {
  int t = threadIdx.x;
  if (t < B_ * 3) {
    int b = t / 3, j = t % 3;
    float s = 0.f;
    for (int k = 0; k < 128; ++k) s += part[(b * 128 + k) * 3 + j];
    out[t] = s * (1.0f / (float)S_) + pb2[j];
  }
}

// ------------------------------------------------------------- launch ----
extern "C" void kernel_launch(void* const* d_in, const int* in_sizes, int n_in,
                              void* d_out, int out_size, void* d_ws, size_t ws_size,
                              hipStream_t stream) {
  const float* x   = (const float*)d_in[0];
  const float* lw1 = (const float*)d_in[1];
  const float* lb1 = (const float*)d_in[2];
  const float* lw2 = (const float*)d_in[3];
  const float* lb2 = (const float*)d_in[4];
  const float* swr = (const float*)d_in[5];
  const float* swi = (const float*)d_in[6];
  const float* skw = (const float*)d_in[7];
  const float* skb = (const float*)d_in[8];
  const float* pw1 = (const float*)d_in[9];
  const float* pb1 = (const float*)d_in[10];
  const float* pw2 = (const float*)d_in[11];
  const float* pb2 = (const float*)d_in[12];
  float*  ws  = (float*)d_ws;
  float*  h   = ws + OFF_H;
  float2* tab = (float2*)(ws + OFF_TAB);

  k_init<<<64, 256, 0, stream>>>(lw2, skw, pw1, ws);
  k_lift<<<dim3(S_ / 256, B_), 256, 0, stream>>>(x, lw1, lb1, lb2,
                                                 ws + OFF_W2T, h);
  for (int l = 0; l < NL; ++l) {
    k_fft_fwd<<<dim3(HID, B_), 256, 0, stream>>>(h, tab, ws + OFF_XFR,
                                                 ws + OFF_XFI);
    k_mix<<<dim3(4, B_), 256, 0, stream>>>(swr + l * HID * HID * MODES,
                                           swi + l * HID * HID * MODES,
                                           ws + OFF_XFR, ws + OFF_XFI,
                                           ws + OFF_YKR, ws + OFF_YKI);
    if (l < NL - 1)
      k_spec_skip<true><<<dim3(S_ / 128, B_), 256, 0, stream>>>(
          ws + OFF_SKWT + l * HID * HID, skb + l * HID,
          ws + OFF_YKR, ws + OFF_YKI, tab, h);
    else
      k_spec_skip<false><<<dim3(S_ / 128, B_), 256, 0, stream>>>(
          ws + OFF_SKWT + l * HID * HID, skb + l * HID,
          ws + OFF_YKR, ws + OFF_YKI, tab, h);
  }
  k_proj<<<dim3(S_ / 128, B_, 4), 256, 0, stream>>>(ws + OFF_PW1T, pb1, pw2, h,
                                                    ws + OFF_PART);
  k_final<<<1, 256, 0, stream>>>(ws + OFF_PART, pb2, (float*)d_out);
}

// Round 4
// 681.338 us; speedup vs baseline: 1.1068x; 1.1068x over previous
//
#include <hip/hip_runtime.h>
#include <math.h>

// Problem constants
#define B_    64
#define S_    4096
#define HID   64
#define LIFT  256
#define MODES 16
#define NL    4

// Workspace layout (float offsets).
#define OFF_H     0
#define OFF_TAB   (B_*HID*S_)                 // float2[4096] = 8192 floats
#define OFF_XFR   (OFF_TAB  + 8192)
#define OFF_XFI   (OFF_XFR  + B_*HID*MODES)   // 65536 each
#define OFF_YKR   (OFF_XFI  + B_*HID*MODES)
#define OFF_YKI   (OFF_YKR  + B_*HID*MODES)
#define OFF_W2T   (OFF_YKI  + B_*HID*MODES)
#define OFF_SKWT  (OFF_W2T  + LIFT*HID)       // 16384
#define OFF_PW1T  (OFF_SKWT + NL*HID*HID)     // 16384
#define OFF_PART  (OFF_PW1T + HID*LIFT)       // 24576 floats: 64*32*4*3

__device__ __forceinline__ float gelu_f(float x) {
  return 0.5f * x * (1.0f + erff(x * 0.70710678118654752440f));
}

// ---------------------------------------------------------------- init ----
__global__ void k_init(const float* __restrict__ lift_w2,
                       const float* __restrict__ skip_w,
                       const float* __restrict__ proj_w1,
                       float* __restrict__ ws) {
  float2* tab  = (float2*)(ws + OFF_TAB);
  float*  w2T  = ws + OFF_W2T;
  float*  skwT = ws + OFF_SKWT;
  float*  pw1T = ws + OFF_PW1T;
  int idx = blockIdx.x * 256 + threadIdx.x;
  int stride = gridDim.x * 256;
  for (int k = idx; k < 4096; k += stride) {
    double th = (2.0 * 3.14159265358979323846 / 4096.0) * (double)k;
    double sn, cn; sincos(th, &sn, &cn);
    tab[k] = make_float2((float)cn, (float)sn);
  }
  for (int k = idx; k < LIFT * HID; k += stride) {     // w2T[c2][o]
    int c2 = k / HID, o = k % HID;
    w2T[k] = lift_w2[o * LIFT + c2];
  }
  for (int k = idx; k < NL * HID * HID; k += stride) { // skwT[l][c][o]
    int l = k / (HID * HID); int r = k % (HID * HID);
    int c = r / HID, o = r % HID;
    skwT[k] = skip_w[l * HID * HID + o * HID + c];
  }
  for (int k = idx; k < HID * LIFT; k += stride) {     // pw1T[c][c2]
    int c = k / LIFT, c2 = k % LIFT;
    pw1T[k] = proj_w1[c2 * HID + c];
  }
}

// ---------------------------------------------------------------- lift ----
// grid (S/128, B), block 256. Tiled: gelu-T chunk (64 c2 x 128 s) in LDS,
// wave owns 16 o rows (scalar W loads), lane owns 2 s columns (acc[16][2]).
__global__ __launch_bounds__(256) void k_lift(
    const float* __restrict__ x, const float* __restrict__ w1,
    const float* __restrict__ b1, const float* __restrict__ b2,
    const float* __restrict__ w2T, float* __restrict__ h) {
  __shared__ float x0[128], x1[128];
  __shared__ float Tl[64 * 128];    // 32 KB
  int tid = threadIdx.x;
  int b = blockIdx.y;
  int s0 = blockIdx.x * 128;
  const int wo = __builtin_amdgcn_readfirstlane((tid >> 6) << 4);
  const int sl = (tid & 63) * 2;
  if (tid < 128) {
    float2 v = ((const float2*)x)[b * S_ + s0 + tid];
    x0[tid] = v.x; x1[tid] = v.y;
  }
  float acc[16][2];
  #pragma unroll
  for (int o = 0; o < 16; ++o) { acc[o][0] = 0.f; acc[o][1] = 0.f; }

  for (int ch = 0; ch < 4; ++ch) {
    __syncthreads();
    // compute gelu tile chunk: c2 = ch*64 + c2l
    int sq = (tid & 31) * 4;
    #pragma unroll
    for (int i = 0; i < 8; ++i) {
      int c2l = i * 8 + (tid >> 5);
      int c2 = ch * 64 + c2l;
      float2 wv = ((const float2*)w1)[c2];
      float bb = b1[c2];
      float4 xv0 = *(const float4*)&x0[sq];
      float4 xv1 = *(const float4*)&x1[sq];
      float4 tv;
      tv.x = gelu_f(wv.x * xv0.x + wv.y * xv1.x + bb);
      tv.y = gelu_f(wv.x * xv0.y + wv.y * xv1.y + bb);
      tv.z = gelu_f(wv.x * xv0.z + wv.y * xv1.z + bb);
      tv.w = gelu_f(wv.x * xv0.w + wv.y * xv1.w + bb);
      *(float4*)&Tl[c2l * 128 + sq] = tv;
    }
    __syncthreads();
    // GEMM over this K-chunk
    #pragma unroll 4
    for (int c = 0; c < 64; ++c) {
      const float* __restrict__ wrow = w2T + (ch * 64 + c) * 64 + wo;
      float w[16];
      #pragma unroll
      for (int o = 0; o < 16; ++o) w[o] = wrow[o];
      float2 hv = *(const float2*)&Tl[c * 128 + sl];
      #pragma unroll
      for (int o = 0; o < 16; ++o) {
        acc[o][0] += w[o] * hv.x;
        acc[o][1] += w[o] * hv.y;
      }
    }
  }
  // epilogue: bias + direct coalesced float2 stores (no LDS round-trip)
  {
    const float* __restrict__ brow = b2 + wo;
    float* __restrict__ hout = h + ((size_t)b * HID + wo) * S_ + s0 + sl;
    #pragma unroll
    for (int o = 0; o < 16; ++o) {
      float bb = brow[o];
      *(float2*)(hout + (size_t)o * S_) =
          make_float2(acc[o][0] + bb, acc[o][1] + bb);
    }
  }
}

// --------------------------------------------------------- forward FFT ----
// grid (HID, B), block 256 = 4 waves. Radix-4 fold over s; wave w owns
// modes m ≡ w (mod 4): {w, w+4, w+8, w+12}. xf[b,i,m] = sum_s h e^{-2πims/S}.
__global__ __launch_bounds__(256) void k_fft_fwd(
    const float* __restrict__ h, const float2* __restrict__ tab,
    float* __restrict__ xfr, float* __restrict__ xfi) {
  __shared__ float hs[S_];          // 16 KB
  int tid = threadIdx.x;
  int i = blockIdx.x, b = blockIdx.y;
  int lane = tid & 63, w = tid >> 6;
  const float4* __restrict__ hp4 = (const float4*)(h + (size_t)(b * HID + i) * S_);
  #pragma unroll
  for (int j = 0; j < 4; ++j)
    ((float4*)hs)[tid + j * 256] = hp4[tid + j * 256];
  __syncthreads();
  float ar[4], ai[4], pr[4], pi[4], rc[4], rs[4];
  #pragma unroll
  for (int jj = 0; jj < 4; ++jj) {
    int m = w + 4 * jj;
    ar[jj] = 0.f; ai[jj] = 0.f;
    float2 p = tab[(m * lane) & 4095];
    pr[jj] = p.x; pi[jj] = -p.y;          // e^{-iθ m lane}
    float2 r = tab[(m * 64) & 4095];
    rc[jj] = r.x; rs[jj] = -r.y;          // step e^{-iθ m 64}
  }
  if (w == 0 || w == 2) {
    for (int k = 0; k < 16; ++k) {
      int base = k * 64 + lane;
      float h0 = hs[base], h1 = hs[base + 1024],
            h2 = hs[base + 2048], h3 = hs[base + 3072];
      float F = (w == 0) ? (h0 + h2) + (h1 + h3) : (h0 + h2) - (h1 + h3);
      #pragma unroll
      for (int jj = 0; jj < 4; ++jj) {
        ar[jj] += F * pr[jj];
        ai[jj] += F * pi[jj];
        float np = pr[jj] * rc[jj] - pi[jj] * rs[jj];
        pi[jj]   = pr[jj] * rs[jj] + pi[jj] * rc[jj];
        pr[jj] = np;
      }
    }
  } else {
    for (int k = 0; k < 16; ++k) {
      int base = k * 64 + lane;
      float h0 = hs[base], h1 = hs[base + 1024],
            h2 = hs[base + 2048], h3 = hs[base + 3072];
      float Fr = h0 - h2;
      float Fi = (w == 1) ? -(h1 - h3) : (h1 - h3);
      #pragma unroll
      for (int jj = 0; jj < 4; ++jj) {
        ar[jj] += Fr * pr[jj] - Fi * pi[jj];
        ai[jj] += Fr * pi[jj] + Fi * pr[jj];
        float np = pr[jj] * rc[jj] - pi[jj] * rs[jj];
        pi[jj]   = pr[jj] * rs[jj] + pi[jj] * rc[jj];
        pr[jj] = np;
      }
    }
  }
  #pragma unroll
  for (int off = 32; off > 0; off >>= 1) {
    #pragma unroll
    for (int jj = 0; jj < 4; ++jj) {
      ar[jj] += __shfl_xor(ar[jj], off, 64);
      ai[jj] += __shfl_xor(ai[jj], off, 64);
    }
  }
  if (lane == 0) {
    int base = (b * HID + i) * MODES;
    #pragma unroll
    for (int jj = 0; jj < 4; ++jj) {
      int m = w + 4 * jj;
      xfr[base + m] = ar[jj];
      xfi[base + m] = ai[jj];   // m=0 path accumulates exact 0 (pi stays 0)
    }
  }
}

// ----------------------------------------------------------- mode mix ----
// grid (4, B), block 256. yk[b][m][o] = fac * sum_i xf[b,i,m]*w[i,o,m]
__global__ __launch_bounds__(256) void k_mix(
    const float* __restrict__ wr_, const float* __restrict__ wi_,
    const float* __restrict__ xfr, const float* __restrict__ xfi,
    float* __restrict__ ykr, float* __restrict__ yki) {
  int tid = threadIdx.x;
  int b = blockIdx.y, pp = blockIdx.x;
  __shared__ float xr[HID * MODES], xi[HID * MODES];
  for (int u = tid; u < HID * MODES; u += 256) {
    xr[u] = xfr[b * HID * MODES + u];
    xi[u] = xfi[b * HID * MODES + u];
  }
  __syncthreads();
  const float invS = 1.0f / (float)S_;
  int o = pp * 16 + (tid >> 4), m = tid & 15;
  float yr = 0.f, yi = 0.f;
  for (int i2 = 0; i2 < HID; ++i2) {
    float wr = wr_[(i2 * HID + o) * MODES + m];
    float wi = wi_[(i2 * HID + o) * MODES + m];
    float xrv = xr[i2 * MODES + m], xiv = xi[i2 * MODES + m];
    yr += xrv * wr - xiv * wi;
    yi += xrv * wi + xiv * wr;
  }
  float fac = (m == 0) ? invS : 2.f * invS;
  ykr[(b * 16 + m) * 64 + o] = yr * fac;
  yki[(b * 16 + m) * 64 + o] = yi * fac;
}

// --------------------------------------------- irfft + skip + (gelu) ----
// grid (S/128, B), block 256, in-place h update. No LDS; one barrier
// separates all in-place reads from stores.
template <bool ACT>
__global__ __launch_bounds__(256) void k_spec_skip(
    const float* __restrict__ skwT, const float* __restrict__ skb,
    const float* __restrict__ ykr, const float* __restrict__ yki,
    const float2* __restrict__ tab, float* __restrict__ h) {
  int tid = threadIdx.x;
  int s0 = blockIdx.x * 128, b = blockIdx.y;
  const int wo = __builtin_amdgcn_readfirstlane((tid >> 6) << 4);
  const int sl = (tid & 63) * 2;
  const int s = s0 + sl;
  float2 t0 = tab[s], t1 = tab[s + 1];
  float bc0 = t0.x, bs0 = t0.y, bc1 = t1.x, bs1 = t1.y;
  float cm0 = bc0, sm0 = bs0, cm1 = bc1, sm1 = bs1;
  float acc[16][2];
  {
    const float* __restrict__ y0 = ykr + (b * 16) * 64 + wo;
    const float* __restrict__ bb = skb + wo;
    #pragma unroll
    for (int o = 0; o < 16; ++o) {
      float v = bb[o] + y0[o];
      acc[o][0] = v; acc[o][1] = v;
    }
  }
  #pragma unroll 1
  for (int m = 1; m < 16; ++m) {
    const float* __restrict__ yr = ykr + (b * 16 + m) * 64 + wo;
    const float* __restrict__ yi = yki + (b * 16 + m) * 64 + wo;
    #pragma unroll
    for (int o = 0; o < 16; ++o) {
      acc[o][0] += yr[o] * cm0 - yi[o] * sm0;
      acc[o][1] += yr[o] * cm1 - yi[o] * sm1;
    }
    float n0 = cm0 * bc0 - sm0 * bs0; sm0 = sm0 * bc0 + cm0 * bs0; cm0 = n0;
    float n1 = cm1 * bc1 - sm1 * bs1; sm1 = sm1 * bc1 + cm1 * bs1; cm1 = n1;
  }
  const float* __restrict__ hcol = h + (size_t)b * HID * S_ + s;
  #pragma unroll 4
  for (int c = 0; c < 64; ++c) {
    const float* __restrict__ wr = skwT + c * 64 + wo;
    float2 hv = *(const float2*)(hcol + (size_t)c * S_);
    #pragma unroll
    for (int o = 0; o < 16; ++o) {
      acc[o][0] += wr[o] * hv.x;
      acc[o][1] += wr[o] * hv.y;
    }
  }
  if (ACT) {
    #pragma unroll
    for (int o = 0; o < 16; ++o) {
      acc[o][0] = gelu_f(acc[o][0]);
      acc[o][1] = gelu_f(acc[o][1]);
    }
  }
  __syncthreads();   // all waves' loads drained before any in-place store
  float* __restrict__ hout = h + ((size_t)b * HID + wo) * S_ + s;
  #pragma unroll
  for (int o = 0; o < 16; ++o)
    *(float2*)(hout + (size_t)o * S_) = make_float2(acc[o][0], acc[o][1]);
}

// ------------------------------------------------- projection + mean ----
// grid (S/128, B, 4). No LDS h-tile: lanes read h direct (float2, L1-reused),
// weights via wave-uniform scalar loads. z picks the 64-c2 quarter.
__global__ __launch_bounds__(256) void k_proj(
    const float* __restrict__ pw1T, const float* __restrict__ pb1,
    const float* __restrict__ pw2, const float* __restrict__ h,
    float* __restrict__ part) {
  __shared__ float red[12];
  int tid = threadIdx.x;
  int s0 = blockIdx.x * 128, b = blockIdx.y;
  int c2base = blockIdx.z * 64;
  const int wo = __builtin_amdgcn_readfirstlane((tid >> 6) << 4);
  const int sl = (tid & 63) * 2;
  float acc[16][2];
  #pragma unroll
  for (int o = 0; o < 16; ++o) { acc[o][0] = 0.f; acc[o][1] = 0.f; }
  const float* __restrict__ hcol = h + (size_t)b * HID * S_ + s0 + sl;
  #pragma unroll 4
  for (int c = 0; c < 64; ++c) {
    const float* __restrict__ wrow = pw1T + c * LIFT + c2base + wo;
    float w[16];
    #pragma unroll
    for (int o = 0; o < 16; ++o) w[o] = wrow[o];
    float2 hv = *(const float2*)(hcol + (size_t)c * S_);
    #pragma unroll
    for (int o = 0; o < 16; ++o) {
      acc[o][0] += w[o] * hv.x;
      acc[o][1] += w[o] * hv.y;
    }
  }
  // epilogue: gelu + contract with pw2, reduce over s and c2
  const float* __restrict__ b1row = pb1 + c2base + wo;
  const float* __restrict__ p0row = pw2 + c2base + wo;
  const float* __restrict__ p1row = pw2 + 256 + c2base + wo;
  const float* __restrict__ p2row = pw2 + 512 + c2base + wo;
  float o0 = 0.f, o1 = 0.f, o2 = 0.f;
  #pragma unroll
  for (int o = 0; o < 16; ++o) {
    float bb = b1row[o];
    float t = gelu_f(acc[o][0] + bb) + gelu_f(acc[o][1] + bb);
    o0 += p0row[o] * t; o1 += p1row[o] * t; o2 += p2row[o] * t;
  }
  #pragma unroll
  for (int off = 32; off > 0; off >>= 1) {
    o0 += __shfl_xor(o0, off, 64);
    o1 += __shfl_xor(o1, off, 64);
    o2 += __shfl_xor(o2, off, 64);
  }
  int lane = tid & 63, wid = tid >> 6;
  if (lane == 0) { red[wid*3+0] = o0; red[wid*3+1] = o1; red[wid*3+2] = o2; }
  __syncthreads();
  if (tid < 3) {
    float s = red[tid] + red[3 + tid] + red[6 + tid] + red[9 + tid];
    part[((b * 32 + blockIdx.x) * 4 + blockIdx.z) * 3 + tid] = s;
  }
}

__global__ void k_final(const float* __restrict__ part,
                        const float* __restrict__ pb2,
                        float* __restrict__ out) {
  int t = threadIdx.x;
  if (t < B_ * 3) {
    int b = t / 3, j = t % 3;
    float s = 0.f;
    for (int k = 0; k < 128; ++k) s += part[(b * 128 + k) * 3 + j];
    out[t] = s * (1.0f / (float)S_) + pb2[j];
  }
}

// ------------------------------------------------------------- launch ----
extern "C" void kernel_launch(void* const* d_in, const int* in_sizes, int n_in,
                              void* d_out, int out_size, void* d_ws, size_t ws_size,
                              hipStream_t stream) {
  const float* x   = (const float*)d_in[0];
  const float* lw1 = (const float*)d_in[1];
  const float* lb1 = (const float*)d_in[2];
  const float* lw2 = (const float*)d_in[3];
  const float* lb2 = (const float*)d_in[4];
  const float* swr = (const float*)d_in[5];
  const float* swi = (const float*)d_in[6];
  const float* skw = (const float*)d_in[7];
  const float* skb = (const float*)d_in[8];
  const float* pw1 = (const float*)d_in[9];
  const float* pb1 = (const float*)d_in[10];
  const float* pw2 = (const float*)d_in[11];
  const float* pb2 = (const float*)d_in[12];
  float*  ws  = (float*)d_ws;
  float*  h   = ws + OFF_H;
  float2* tab = (float2*)(ws + OFF_TAB);

  k_init<<<64, 256, 0, stream>>>(lw2, skw, pw1, ws);
  k_lift<<<dim3(S_ / 128, B_), 256, 0, stream>>>(x, lw1, lb1, lb2,
                                                 ws + OFF_W2T, h);
  for (int l = 0; l < NL; ++l) {
    k_fft_fwd<<<dim3(HID, B_), 256, 0, stream>>>(h, tab, ws + OFF_XFR,
                                                 ws + OFF_XFI);
    k_mix<<<dim3(4, B_), 256, 0, stream>>>(swr + l * HID * HID * MODES,
                                           swi + l * HID * HID * MODES,
                                           ws + OFF_XFR, ws + OFF_XFI,
                                           ws + OFF_YKR, ws + OFF_YKI);
    if (l < NL - 1)
      k_spec_skip<true><<<dim3(S_ / 128, B_), 256, 0, stream>>>(
          ws + OFF_SKWT + l * HID * HID, skb + l * HID,
          ws + OFF_YKR, ws + OFF_YKI, tab, h);
    else
      k_spec_skip<false><<<dim3(S_ / 128, B_), 256, 0, stream>>>(
          ws + OFF_SKWT + l * HID * HID, skb + l * HID,
          ws + OFF_YKR, ws + OFF_YKI, tab, h);
  }
  k_proj<<<dim3(S_ / 128, B_, 4), 256, 0, stream>>>(ws + OFF_PW1T, pb1, pw2, h,
                                                    ws + OFF_PART);
  k_final<<<1, 256, 0, stream>>>(ws + OFF_PART, pb2, (float*)d_out);
}